// Round 4
// baseline (315.471 us; speedup 1.0000x reference)
//
#include <hip/hip_runtime.h>
#include <hip/hip_bf16.h>

#define BSZ 8
#define CDIM 512
#define KDIM 512
#define HWSZ 16384   // 128*128
#define NPIX (BSZ*HWSZ)  // 131072

#define ROWU 20      // LDS row stride in u32 (80 B): 16B-aligned, ~2-way (free) r/w

using bf16x8 = __attribute__((ext_vector_type(8))) short;
using f32x4  = __attribute__((ext_vector_type(4))) float;

// ---------------- prep: Eb[k][c] = bf16( E[k][c] / ||E[k]|| ) ----------------
__global__ __launch_bounds__(64) void prep_emb_kernel(const float* __restrict__ E,
                                                      unsigned short* __restrict__ Eb) {
  int k = blockIdx.x;
  int lane = threadIdx.x;
  const float4* row = (const float4*)(E + (size_t)k * CDIM);
  float4 v0 = row[lane * 2], v1 = row[lane * 2 + 1];
  float ss = v0.x*v0.x + v0.y*v0.y + v0.z*v0.z + v0.w*v0.w
           + v1.x*v1.x + v1.y*v1.y + v1.z*v1.z + v1.w*v1.w;
  #pragma unroll
  for (int d = 1; d < 64; d <<= 1) ss += __shfl_xor(ss, d, 64);
  float rinv = rsqrtf(fmaxf(ss, 1e-24f));
  float f[8] = {v0.x, v0.y, v0.z, v0.w, v1.x, v1.y, v1.z, v1.w};
  unsigned o[8];
  #pragma unroll
  for (int e = 0; e < 8; ++e) {
    float x = f[e] * rinv;
    unsigned u = __builtin_bit_cast(unsigned, x);
    o[e] = (u + 0x7FFFu + ((u >> 16) & 1u)) >> 16;   // RNE f32->bf16
  }
  uint4 pack;
  pack.x = o[0] | (o[1] << 16);
  pack.y = o[2] | (o[3] << 16);
  pack.z = o[4] | (o[5] << 16);
  pack.w = o[6] | (o[7] << 16);
  ((uint4*)(Eb + (size_t)k * CDIM))[lane] = pack;
}

// ---------------- fused: X->(LDS transpose+bf16)->GEMM->argmax->counts  +  ANN gt-stream ----------------
// block = 512 threads = 8 waves; wave wv owns k-cols [wv*64, wv*64+64); block owns 64 px.
// Role split: waves 0-3 stage X slices into LDS; waves 4-7 stream this block's 128KB ANN
// chunk (gt_count). All 8 waves run the MFMA ladder. acc[4][4]=64 AGPR -> <=128 regs
// -> 4 waves/SIMD (16 waves/CU).
__global__ __launch_bounds__(512, 4) void gemm_fused(
    const float* __restrict__ X, const float* __restrict__ ANN,
    const unsigned short* __restrict__ Eb,
    float* __restrict__ gt_count,
    int* __restrict__ pred_count, int* __restrict__ inter) {
  __shared__ unsigned int lds[2][64 * ROWU];
  __shared__ float s_v[8][64];
  __shared__ int   s_k[8][64];
  int tid  = threadIdx.x;
  int wv   = tid >> 6;          // 0..7: k-group of 64
  int lane = tid & 63;
  int p15  = lane & 15, q = lane >> 4;
  int px0  = blockIdx.x * 64;
  int b    = px0 >> 14;
  int hw   = px0 & (HWSZ - 1);

  bool stager = (tid < 256);
  int cp = tid & 15;            // c-pair 0..15
  int pq = (tid >> 4) & 15;     // px-quad 0..15
  const float* Xs = X + ((size_t)b * CDIM + 2 * cp) * HWSZ + hw + 4 * pq;

  // ANN chunk: block covers floats [bid*32768, bid*32768+32768) = 2 exact (b,k) slices
  const float* Ap = ANN + (size_t)blockIdx.x * 32768 + (size_t)(tid & 255) * 4;
  float annAcc0 = 0.f, annAcc1 = 0.f;

  const unsigned short* Er = Eb + (size_t)(wv * 64 + p15) * CDIM + q * 8;

  // ---- stage slice 0 into lds[0] (waves 0-3) ----
  if (stager) {
    float4 v0 = *(const float4*)Xs;
    float4 v1 = *(const float4*)(Xs + HWSZ);
    float f0[4] = {v0.x, v0.y, v0.z, v0.w};
    float f1[4] = {v1.x, v1.y, v1.z, v1.w};
    #pragma unroll
    for (int j = 0; j < 4; ++j) {
      unsigned u = (__builtin_bit_cast(unsigned, f0[j]) >> 16)
                 | (__builtin_bit_cast(unsigned, f1[j]) & 0xFFFF0000u);
      lds[0][(4 * pq + j) * ROWU + cp] = u;   // row = px-local, col = c-pair
    }
  }

  f32x4 acc[4][4];
  #pragma unroll
  for (int m = 0; m < 4; ++m)
    #pragma unroll
    for (int n = 0; n < 4; ++n)
      acc[m][n] = (f32x4){0.f, 0.f, 0.f, 0.f};

  for (int cs = 0; cs < 16; ++cs) {
    int cur = cs & 1;
    // B frags for this slice (L2-resident) — issued before barrier
    bf16x8 bb[4];
    #pragma unroll
    for (int n = 0; n < 4; ++n)
      bb[n] = *(const bf16x8*)(Er + (size_t)n * 16 * CDIM + cs * 32);
    // role-split memory work: X prefetch (waves 0-3) / ANN stream (waves 4-7)
    float4 w0, w1;
    if (stager) {
      if (cs < 15) {
        const float* nsrc = Xs + (size_t)(cs + 1) * 32 * HWSZ;
        w0 = *(const float4*)nsrc;
        w1 = *(const float4*)(nsrc + HWSZ);
      }
    } else {
      w0 = *(const float4*)(Ap + cs * 2048);
      w1 = *(const float4*)(Ap + cs * 2048 + 1024);
    }
    __syncthreads();                       // lds[cur] ready for all waves
    bf16x8 a[4];
    #pragma unroll
    for (int m = 0; m < 4; ++m)
      a[m] = *(bf16x8*)&lds[cur][(m * 16 + p15) * ROWU + q * 4];  // ds_read_b128
    __builtin_amdgcn_s_setprio(1);
    #pragma unroll
    for (int n = 0; n < 4; ++n)
      #pragma unroll
      for (int m = 0; m < 4; ++m)
        acc[m][n] = __builtin_amdgcn_mfma_f32_16x16x32_bf16(a[m], bb[n], acc[m][n], 0, 0, 0);
    __builtin_amdgcn_s_setprio(0);
    if (stager) {
      if (cs < 15) {
        float f0[4] = {w0.x, w0.y, w0.z, w0.w};
        float f1[4] = {w1.x, w1.y, w1.z, w1.w};
        #pragma unroll
        for (int j = 0; j < 4; ++j) {
          unsigned u = (__builtin_bit_cast(unsigned, f0[j]) >> 16)
                     | (__builtin_bit_cast(unsigned, f1[j]) & 0xFFFF0000u);
          lds[cur ^ 1][(4 * pq + j) * ROWU + cp] = u;
        }
      }
    } else {
      float s = (w0.x + w0.y) + (w0.z + w0.w) + (w1.x + w1.y) + (w1.z + w1.w);
      if (cs < 8) annAcc0 += s; else annAcc1 += s;   // slice boundary at cs=8 (16384 floats)
    }
  }

  // ---- gt_count contribution (waves 4-7): exact integer sums ----
  if (!stager) {
    #pragma unroll
    for (int d = 1; d < 64; d <<= 1) {
      annAcc0 += __shfl_xor(annAcc0, d, 64);
      annAcc1 += __shfl_xor(annAcc1, d, 64);
    }
    if (lane == 0) {
      atomicAdd(&gt_count[(blockIdx.x * 2)     & (KDIM - 1)], annAcc0);
      atomicAdd(&gt_count[(blockIdx.x * 2 + 1) & (KDIM - 1)], annAcc1);
    }
  }

  // ---- argmax epilogue: D layout col(k)=lane&15, row(px)=(lane>>4)*4+reg ----
  #pragma unroll
  for (int m = 0; m < 4; ++m) {
    #pragma unroll
    for (int r = 0; r < 4; ++r) {
      float best = acc[m][0][r];
      int bn = 0;
      #pragma unroll
      for (int n = 1; n < 4; ++n) {
        float v = acc[m][n][r];
        if (v > best) { best = v; bn = n; }
      }
      int bk = wv * 64 + bn * 16 + p15;
      #pragma unroll
      for (int d = 1; d < 16; d <<= 1) {   // butterfly over 16 k-col lanes
        float ov = __shfl_xor(best, d, 64);
        int   ok = __shfl_xor(bk, d, 64);
        if (ov > best || (ov == best && ok < bk)) { best = ov; bk = ok; }
      }
      if (p15 == 0) {
        int p = m * 16 + q * 4 + r;        // pixel within block
        s_v[wv][p] = best;
        s_k[wv][p] = bk;
      }
    }
  }
  __syncthreads();
  if (tid < 64) {
    int p = tid;
    float best = s_v[0][p]; int bk = s_k[0][p];
    #pragma unroll
    for (int w = 1; w < 8; ++w) {
      float v = s_v[w][p]; int kk = s_k[w][p];
      if (v > best || (v == best && kk < bk)) { best = v; bk = kk; }
    }
    atomicAdd(&pred_count[bk], 1);
    float g = ANN[((size_t)b * KDIM + bk) * HWSZ + hw + p];   // one-hot gather
    if (g > 0.5f) atomicAdd(&inter[bk], 1);
  }
}

// ---------------- final dice reduction ----------------
__global__ __launch_bounds__(512) void final_kernel(
    const int* __restrict__ pred_count, const int* __restrict__ inter,
    const float* __restrict__ gt_count, float* __restrict__ out) {
  int k = threadIdx.x;
  float G = gt_count[k];
  float P = (float)pred_count[k];
  float I = (float)inter[k];
  float card  = P + G;
  float score = (2.f * I + 1e-4f) / fmaxf(card + 1e-4f, 1e-7f);
  float v = (G > 0.f) ? (1.f - score) : 0.f;
  #pragma unroll
  for (int d = 1; d < 64; d <<= 1) v += __shfl_xor(v, d, 64);
  __shared__ float sw[8];
  if ((k & 63) == 0) sw[k >> 6] = v;
  __syncthreads();
  if (k == 0) {
    float s = 0.f;
    #pragma unroll
    for (int i = 0; i < 8; ++i) s += sw[i];
    out[0] = s / (float)KDIM;
  }
}

extern "C" void kernel_launch(void* const* d_in, const int* in_sizes, int n_in,
                              void* d_out, int out_size, void* d_ws, size_t ws_size,
                              hipStream_t stream) {
  const float* X   = (const float*)d_in[0];   // [8,512,128,128] fp32
  const float* ANN = (const float*)d_in[1];   // [8,512,128,128] fp32 one-hot
  const float* E   = (const float*)d_in[2];   // [512,512] fp32

  char* base = (char*)d_ws;
  unsigned short* Eb = (unsigned short*)base;                 // 512 KiB
  float* gt_count    = (float*)(base + 524288);
  int*   pred_count  = (int*)  (base + 524288 + 2048);
  int*   inter       = (int*)  (base + 524288 + 4096);

  hipMemsetAsync(base + 524288, 0, 6144, stream);
  prep_emb_kernel<<<KDIM, 64, 0, stream>>>(E, Eb);
  gemm_fused<<<NPIX / 64, 512, 0, stream>>>(X, ANN, Eb, gt_count, pred_count, inter);
  final_kernel<<<1, 512, 0, stream>>>(pred_count, inter, gt_count, (float*)d_out);
}

// Round 5
// 257.112 us; speedup vs baseline: 1.2270x; 1.2270x over previous
//
#include <hip/hip_runtime.h>
#include <hip/hip_bf16.h>

#define BSZ 8
#define CDIM 512
#define KDIM 512
#define HWSZ 16384   // 128*128
#define NPIX (BSZ*HWSZ)  // 131072

#define ROWU 36      // 64c = 32 u32 + 4 pad; stride%32==4 -> 2-way (free) LDS r/w

using bf16x8 = __attribute__((ext_vector_type(8))) short;
using f32x4  = __attribute__((ext_vector_type(4))) float;

__device__ __forceinline__ unsigned pack2bf16(float lo, float hi) {
  // truncating f32->bf16 pair pack: lo -> bits[15:0], hi -> bits[31:16]
  return (__builtin_bit_cast(unsigned, lo) >> 16) |
         (__builtin_bit_cast(unsigned, hi) & 0xFFFF0000u);
}

// ---------------- prep: Eb[k][c] = bf16( E[k][c] / ||E[k]|| ) ----------------
__global__ __launch_bounds__(64) void prep_emb_kernel(const float* __restrict__ E,
                                                      unsigned short* __restrict__ Eb) {
  int k = blockIdx.x;
  int lane = threadIdx.x;
  const float4* row = (const float4*)(E + (size_t)k * CDIM);
  float4 v0 = row[lane * 2], v1 = row[lane * 2 + 1];
  float ss = v0.x*v0.x + v0.y*v0.y + v0.z*v0.z + v0.w*v0.w
           + v1.x*v1.x + v1.y*v1.y + v1.z*v1.z + v1.w*v1.w;
  #pragma unroll
  for (int d = 1; d < 64; d <<= 1) ss += __shfl_xor(ss, d, 64);
  float rinv = rsqrtf(fmaxf(ss, 1e-24f));
  float f[8] = {v0.x, v0.y, v0.z, v0.w, v1.x, v1.y, v1.z, v1.w};
  unsigned o[8];
  #pragma unroll
  for (int e = 0; e < 8; ++e) {
    float x = f[e] * rinv;
    unsigned u = __builtin_bit_cast(unsigned, x);
    o[e] = (u + 0x7FFFu + ((u >> 16) & 1u)) >> 16;   // RNE f32->bf16
  }
  uint4 pack;
  pack.x = o[0] | (o[1] << 16);
  pack.y = o[2] | (o[3] << 16);
  pack.z = o[4] | (o[5] << 16);
  pack.w = o[6] | (o[7] << 16);
  ((uint4*)(Eb + (size_t)k * CDIM))[lane] = pack;
}

// ---------------- fused: ANN gt-stream (prologue) + X->(LDS T+bf16)->GEMM->argmax ----------------
// block = 256 threads = 4 waves; wave wv owns k-cols [wv*128, wv*128+128); block owns 64 px.
// K(=C) in 8 iterations of 64 c, double-buffered LDS, 1 barrier per iteration.
__global__ __launch_bounds__(256, 2) void gemm_fused(
    const float* __restrict__ X, const float* __restrict__ ANN,
    const unsigned short* __restrict__ Eb,
    float* __restrict__ gt_count,
    int* __restrict__ pred_count, int* __restrict__ inter) {
  __shared__ unsigned int lds[2][64 * ROWU];
  __shared__ float s_v[4][64];
  __shared__ int   s_k[4][64];
  int tid  = threadIdx.x;
  int wv   = tid >> 6;          // k-group 0..3 (128 k each)
  int lane = tid & 63;
  int p15  = lane & 15, q = lane >> 4;
  int cp   = tid & 15;          // c-pair 0..15
  int pq   = tid >> 4;          // px-quad 0..15
  int px0  = blockIdx.x * 64;
  int b    = px0 >> 14;
  int hw   = px0 & (HWSZ - 1);

  // ---- phase 1: gt-count stream, this block's 2 exact (b,k) ANN slices ----
  // barrier-free, high-MLP; overlaps other resident blocks' GEMM latency stalls
  {
    const float* Ap = ANN + (size_t)blockIdx.x * 32768 + tid * 4;
    float s0 = 0.f, s1 = 0.f;
    #pragma unroll
    for (int r = 0; r < 16; ++r) {
      float4 u = *(const float4*)(Ap + (size_t)r * 1024);
      float4 v = *(const float4*)(Ap + 16384 + (size_t)r * 1024);
      s0 += (u.x + u.y) + (u.z + u.w);
      s1 += (v.x + v.y) + (v.z + v.w);
    }
    #pragma unroll
    for (int d = 1; d < 64; d <<= 1) {
      s0 += __shfl_xor(s0, d, 64);
      s1 += __shfl_xor(s1, d, 64);
    }
    if (lane == 0) {   // exact integer partials -> float atomics order-independent
      atomicAdd(&gt_count[(blockIdx.x * 2)     & (KDIM - 1)], s0);
      atomicAdd(&gt_count[(blockIdx.x * 2 + 1) & (KDIM - 1)], s1);
    }
  }

  // ---- phase 2: GEMM ----
  const float*          Xs = X  + ((size_t)b * CDIM + 2 * cp) * HWSZ + hw + 4 * pq;
  const unsigned short* Er = Eb + (size_t)(wv * 128 + p15) * CDIM + q * 8;

  // stage iteration 0 (64 c) into lds[0]: thread covers c-pairs cp and cp+16
  {
    float4 w0 = *(const float4*)(Xs);
    float4 w1 = *(const float4*)(Xs + HWSZ);
    float4 w2 = *(const float4*)(Xs + 32 * HWSZ);
    float4 w3 = *(const float4*)(Xs + 33 * HWSZ);
    float f0[4] = {w0.x, w0.y, w0.z, w0.w}, f1[4] = {w1.x, w1.y, w1.z, w1.w};
    float f2[4] = {w2.x, w2.y, w2.z, w2.w}, f3[4] = {w3.x, w3.y, w3.z, w3.w};
    #pragma unroll
    for (int j = 0; j < 4; ++j) {
      lds[0][(4 * pq + j) * ROWU + cp]      = pack2bf16(f0[j], f1[j]);
      lds[0][(4 * pq + j) * ROWU + 16 + cp] = pack2bf16(f2[j], f3[j]);
    }
  }

  f32x4 acc[4][8];
  #pragma unroll
  for (int m = 0; m < 4; ++m)
    #pragma unroll
    for (int n = 0; n < 8; ++n)
      acc[m][n] = (f32x4){0.f, 0.f, 0.f, 0.f};

  #pragma unroll 2
  for (int i = 0; i < 8; ++i) {
    int cur = i & 1;
    // prefetch next iteration's 64-c X slab (4 float4 in flight)
    float4 w0, w1, w2, w3;
    if (i < 7) {
      const float* nx = Xs + (size_t)(i + 1) * 64 * HWSZ;
      w0 = *(const float4*)(nx);
      w1 = *(const float4*)(nx + HWSZ);
      w2 = *(const float4*)(nx + 32 * HWSZ);
      w3 = *(const float4*)(nx + 33 * HWSZ);
    }
    __syncthreads();                       // lds[cur] ready
    #pragma unroll
    for (int h = 0; h < 2; ++h) {          // two 32-c halves per iteration
      bf16x8 bb[8];
      #pragma unroll
      for (int n = 0; n < 8; ++n)
        bb[n] = *(const bf16x8*)(Er + (size_t)n * 16 * CDIM + i * 64 + h * 32);
      bf16x8 a[4];
      #pragma unroll
      for (int m = 0; m < 4; ++m)
        a[m] = *(bf16x8*)&lds[cur][(m * 16 + p15) * ROWU + h * 16 + q * 4];
      #pragma unroll
      for (int n = 0; n < 8; ++n)
        #pragma unroll
        for (int m = 0; m < 4; ++m)
          acc[m][n] = __builtin_amdgcn_mfma_f32_16x16x32_bf16(a[m], bb[n], acc[m][n], 0, 0, 0);
    }
    // write prefetched slab into the other buffer
    if (i < 7) {
      float f0[4] = {w0.x, w0.y, w0.z, w0.w}, f1[4] = {w1.x, w1.y, w1.z, w1.w};
      float f2[4] = {w2.x, w2.y, w2.z, w2.w}, f3[4] = {w3.x, w3.y, w3.z, w3.w};
      #pragma unroll
      for (int j = 0; j < 4; ++j) {
        lds[cur ^ 1][(4 * pq + j) * ROWU + cp]      = pack2bf16(f0[j], f1[j]);
        lds[cur ^ 1][(4 * pq + j) * ROWU + 16 + cp] = pack2bf16(f2[j], f3[j]);
      }
    }
  }

  // ---- argmax epilogue: D layout col(k)=lane&15, row(px)=(lane>>4)*4+reg ----
  #pragma unroll
  for (int m = 0; m < 4; ++m) {
    #pragma unroll
    for (int r = 0; r < 4; ++r) {
      float best = acc[m][0][r];
      int bn = 0;
      #pragma unroll
      for (int n = 1; n < 8; ++n) {
        float v = acc[m][n][r];
        if (v > best) { best = v; bn = n; }
      }
      int bk = wv * 128 + bn * 16 + p15;
      #pragma unroll
      for (int d = 1; d < 16; d <<= 1) {   // butterfly over 16 k-col lanes
        float ov = __shfl_xor(best, d, 64);
        int   ok = __shfl_xor(bk, d, 64);
        if (ov > best || (ov == best && ok < bk)) { best = ov; bk = ok; }
      }
      if (p15 == 0) {
        int p = m * 16 + q * 4 + r;        // pixel within block
        s_v[wv][p] = best;
        s_k[wv][p] = bk;
      }
    }
  }
  __syncthreads();
  if (tid < 64) {
    int p = tid;
    float best = s_v[0][p]; int bk = s_k[0][p];
    #pragma unroll
    for (int w = 1; w < 4; ++w) {
      float v = s_v[w][p]; int kk = s_k[w][p];
      if (v > best || (v == best && kk < bk)) { best = v; bk = kk; }
    }
    atomicAdd(&pred_count[bk], 1);
    float g = ANN[((size_t)b * KDIM + bk) * HWSZ + hw + p];   // one-hot gather
    if (g > 0.5f) atomicAdd(&inter[bk], 1);
  }
}

// ---------------- final dice reduction ----------------
__global__ __launch_bounds__(512) void final_kernel(
    const int* __restrict__ pred_count, const int* __restrict__ inter,
    const float* __restrict__ gt_count, float* __restrict__ out) {
  int k = threadIdx.x;
  float G = gt_count[k];
  float P = (float)pred_count[k];
  float I = (float)inter[k];
  float card  = P + G;
  float score = (2.f * I + 1e-4f) / fmaxf(card + 1e-4f, 1e-7f);
  float v = (G > 0.f) ? (1.f - score) : 0.f;
  #pragma unroll
  for (int d = 1; d < 64; d <<= 1) v += __shfl_xor(v, d, 64);
  __shared__ float sw[8];
  if ((k & 63) == 0) sw[k >> 6] = v;
  __syncthreads();
  if (k == 0) {
    float s = 0.f;
    #pragma unroll
    for (int i = 0; i < 8; ++i) s += sw[i];
    out[0] = s / (float)KDIM;
  }
}

extern "C" void kernel_launch(void* const* d_in, const int* in_sizes, int n_in,
                              void* d_out, int out_size, void* d_ws, size_t ws_size,
                              hipStream_t stream) {
  const float* X   = (const float*)d_in[0];   // [8,512,128,128] fp32
  const float* ANN = (const float*)d_in[1];   // [8,512,128,128] fp32 one-hot
  const float* E   = (const float*)d_in[2];   // [512,512] fp32

  char* base = (char*)d_ws;
  unsigned short* Eb = (unsigned short*)base;                 // 512 KiB
  float* gt_count    = (float*)(base + 524288);
  int*   pred_count  = (int*)  (base + 524288 + 2048);
  int*   inter       = (int*)  (base + 524288 + 4096);

  hipMemsetAsync(base + 524288, 0, 6144, stream);
  prep_emb_kernel<<<KDIM, 64, 0, stream>>>(E, Eb);
  gemm_fused<<<NPIX / 64, 256, 0, stream>>>(X, ANN, Eb, gt_count, pred_count, inter);
  final_kernel<<<1, 512, 0, stream>>>(pred_count, inter, gt_count, (float*)d_out);
}

// Round 6
// 256.728 us; speedup vs baseline: 1.2288x; 1.0015x over previous
//
#include <hip/hip_runtime.h>
#include <hip/hip_bf16.h>

#define BSZ 8
#define CDIM 512
#define KDIM 512
#define HWSZ 16384   // 128*128
#define NPIX (BSZ*HWSZ)  // 131072

#define ROWU 36      // 64c = 32 u32 + 4 pad; stride%32==4 -> 2-way (free) LDS r/w

using bf16x8 = __attribute__((ext_vector_type(8))) short;
using f32x4  = __attribute__((ext_vector_type(4))) float;

__device__ __forceinline__ unsigned pack2bf16(float lo, float hi) {
  // truncating f32->bf16 pair pack: lo -> bits[15:0], hi -> bits[31:16]
  return (__builtin_bit_cast(unsigned, lo) >> 16) |
         (__builtin_bit_cast(unsigned, hi) & 0xFFFF0000u);
}

// ---------------- prep: Eb[k][c] = bf16( E[k][c] / ||E[k]|| ) ----------------
__global__ __launch_bounds__(64) void prep_emb_kernel(const float* __restrict__ E,
                                                      unsigned short* __restrict__ Eb) {
  int k = blockIdx.x;
  int lane = threadIdx.x;
  const float4* row = (const float4*)(E + (size_t)k * CDIM);
  float4 v0 = row[lane * 2], v1 = row[lane * 2 + 1];
  float ss = v0.x*v0.x + v0.y*v0.y + v0.z*v0.z + v0.w*v0.w
           + v1.x*v1.x + v1.y*v1.y + v1.z*v1.z + v1.w*v1.w;
  #pragma unroll
  for (int d = 1; d < 64; d <<= 1) ss += __shfl_xor(ss, d, 64);
  float rinv = rsqrtf(fmaxf(ss, 1e-24f));
  float f[8] = {v0.x, v0.y, v0.z, v0.w, v1.x, v1.y, v1.z, v1.w};
  unsigned o[8];
  #pragma unroll
  for (int e = 0; e < 8; ++e) {
    float x = f[e] * rinv;
    unsigned u = __builtin_bit_cast(unsigned, x);
    o[e] = (u + 0x7FFFu + ((u >> 16) & 1u)) >> 16;   // RNE f32->bf16
  }
  uint4 pack;
  pack.x = o[0] | (o[1] << 16);
  pack.y = o[2] | (o[3] << 16);
  pack.z = o[4] | (o[5] << 16);
  pack.w = o[6] | (o[7] << 16);
  ((uint4*)(Eb + (size_t)k * CDIM))[lane] = pack;
}

// ---------------- fused: ANN gt-stream (prologue) + X->(LDS T+bf16)->GEMM->argmax ----------------
// block = 256 threads = 4 waves; wave wv owns k-cols [wv*128, wv*128+128); block owns 64 px.
// K(=C) in 8 iterations of 64 c, double-buffered LDS, 1 barrier per iteration.
__global__ __launch_bounds__(256, 2) void gemm_fused(
    const float* __restrict__ X, const float* __restrict__ ANN,
    const unsigned short* __restrict__ Eb,
    float* __restrict__ gt_count,
    int* __restrict__ pred_count, int* __restrict__ inter) {
  __shared__ unsigned int lds[2][64 * ROWU];
  __shared__ float s_v[4][64];
  __shared__ int   s_k[4][64];
  int tid  = threadIdx.x;
  int wv   = tid >> 6;          // k-group 0..3 (128 k each)
  int lane = tid & 63;
  int p15  = lane & 15, q = lane >> 4;
  int cp   = tid & 15;          // c-pair 0..15
  int pq   = tid >> 4;          // px-quad 0..15
  int px0  = blockIdx.x * 64;
  int b    = px0 >> 14;
  int hw   = px0 & (HWSZ - 1);

  // ---- phase 1: gt-count stream, this block's 2 exact (b,k) ANN slices ----
  // barrier-free, high-MLP; overlaps other resident blocks' GEMM latency stalls
  {
    const float* Ap = ANN + (size_t)blockIdx.x * 32768 + tid * 4;
    float s0 = 0.f, s1 = 0.f;
    #pragma unroll
    for (int r = 0; r < 16; ++r) {
      float4 u = *(const float4*)(Ap + (size_t)r * 1024);
      float4 v = *(const float4*)(Ap + 16384 + (size_t)r * 1024);
      s0 += (u.x + u.y) + (u.z + u.w);
      s1 += (v.x + v.y) + (v.z + v.w);
    }
    #pragma unroll
    for (int d = 1; d < 64; d <<= 1) {
      s0 += __shfl_xor(s0, d, 64);
      s1 += __shfl_xor(s1, d, 64);
    }
    if (lane == 0) {   // exact integer partials -> float atomics order-independent
      atomicAdd(&gt_count[(blockIdx.x * 2)     & (KDIM - 1)], s0);
      atomicAdd(&gt_count[(blockIdx.x * 2 + 1) & (KDIM - 1)], s1);
    }
  }

  // ---- phase 2: GEMM ----
  const float*          Xs = X  + ((size_t)b * CDIM + 2 * cp) * HWSZ + hw + 4 * pq;
  const unsigned short* Er = Eb + (size_t)(wv * 128 + p15) * CDIM + q * 8;

  // stage iteration 0 (64 c) into lds[0]: thread covers c-pairs cp and cp+16
  {
    float4 w0 = *(const float4*)(Xs);
    float4 w1 = *(const float4*)(Xs + HWSZ);
    float4 w2 = *(const float4*)(Xs + 32 * HWSZ);
    float4 w3 = *(const float4*)(Xs + 33 * HWSZ);
    float f0[4] = {w0.x, w0.y, w0.z, w0.w}, f1[4] = {w1.x, w1.y, w1.z, w1.w};
    float f2[4] = {w2.x, w2.y, w2.z, w2.w}, f3[4] = {w3.x, w3.y, w3.z, w3.w};
    #pragma unroll
    for (int j = 0; j < 4; ++j) {
      lds[0][(4 * pq + j) * ROWU + cp]      = pack2bf16(f0[j], f1[j]);
      lds[0][(4 * pq + j) * ROWU + 16 + cp] = pack2bf16(f2[j], f3[j]);
    }
  }

  f32x4 acc[4][8];
  #pragma unroll
  for (int m = 0; m < 4; ++m)
    #pragma unroll
    for (int n = 0; n < 8; ++n)
      acc[m][n] = (f32x4){0.f, 0.f, 0.f, 0.f};

  #pragma unroll 2
  for (int i = 0; i < 8; ++i) {
    int cur = i & 1;
    // prefetch next iteration's 64-c X slab (4 float4 in flight)
    float4 w0, w1, w2, w3;
    if (i < 7) {
      const float* nx = Xs + (size_t)(i + 1) * 64 * HWSZ;
      w0 = *(const float4*)(nx);
      w1 = *(const float4*)(nx + HWSZ);
      w2 = *(const float4*)(nx + 32 * HWSZ);
      w3 = *(const float4*)(nx + 33 * HWSZ);
    }
    __syncthreads();                       // lds[cur] ready
    #pragma unroll
    for (int h = 0; h < 2; ++h) {          // two 32-c halves per iteration
      bf16x8 bb[8];
      #pragma unroll
      for (int n = 0; n < 8; ++n)
        bb[n] = *(const bf16x8*)(Er + (size_t)n * 16 * CDIM + i * 64 + h * 32);
      bf16x8 a[4];
      #pragma unroll
      for (int m = 0; m < 4; ++m)
        a[m] = *(bf16x8*)&lds[cur][(m * 16 + p15) * ROWU + h * 16 + q * 4];
      #pragma unroll
      for (int n = 0; n < 8; ++n)
        #pragma unroll
        for (int m = 0; m < 4; ++m)
          acc[m][n] = __builtin_amdgcn_mfma_f32_16x16x32_bf16(a[m], bb[n], acc[m][n], 0, 0, 0);
    }
    // write prefetched slab into the other buffer
    if (i < 7) {
      float f0[4] = {w0.x, w0.y, w0.z, w0.w}, f1[4] = {w1.x, w1.y, w1.z, w1.w};
      float f2[4] = {w2.x, w2.y, w2.z, w2.w}, f3[4] = {w3.x, w3.y, w3.z, w3.w};
      #pragma unroll
      for (int j = 0; j < 4; ++j) {
        lds[cur ^ 1][(4 * pq + j) * ROWU + cp]      = pack2bf16(f0[j], f1[j]);
        lds[cur ^ 1][(4 * pq + j) * ROWU + 16 + cp] = pack2bf16(f2[j], f3[j]);
      }
    }
  }

  // ---- argmax epilogue: D layout col(k)=lane&15, row(px)=(lane>>4)*4+reg ----
  #pragma unroll
  for (int m = 0; m < 4; ++m) {
    #pragma unroll
    for (int r = 0; r < 4; ++r) {
      float best = acc[m][0][r];
      int bn = 0;
      #pragma unroll
      for (int n = 1; n < 8; ++n) {
        float v = acc[m][n][r];
        if (v > best) { best = v; bn = n; }
      }
      int bk = wv * 128 + bn * 16 + p15;
      #pragma unroll
      for (int d = 1; d < 16; d <<= 1) {   // butterfly over 16 k-col lanes
        float ov = __shfl_xor(best, d, 64);
        int   ok = __shfl_xor(bk, d, 64);
        if (ov > best || (ov == best && ok < bk)) { best = ov; bk = ok; }
      }
      if (p15 == 0) {
        int p = m * 16 + q * 4 + r;        // pixel within block
        s_v[wv][p] = best;
        s_k[wv][p] = bk;
      }
    }
  }
  __syncthreads();
  if (tid < 64) {
    int p = tid;
    float best = s_v[0][p]; int bk = s_k[0][p];
    #pragma unroll
    for (int w = 1; w < 4; ++w) {
      float v = s_v[w][p]; int kk = s_k[w][p];
      if (v > best || (v == best && kk < bk)) { best = v; bk = kk; }
    }
    atomicAdd(&pred_count[bk], 1);
    float g = ANN[((size_t)b * KDIM + bk) * HWSZ + hw + p];   // one-hot gather
    if (g > 0.5f) atomicAdd(&inter[bk], 1);
  }
}

// ---------------- final dice reduction ----------------
__global__ __launch_bounds__(512) void final_kernel(
    const int* __restrict__ pred_count, const int* __restrict__ inter,
    const float* __restrict__ gt_count, float* __restrict__ out) {
  int k = threadIdx.x;
  float G = gt_count[k];
  float P = (float)pred_count[k];
  float I = (float)inter[k];
  float card  = P + G;
  float score = (2.f * I + 1e-4f) / fmaxf(card + 1e-4f, 1e-7f);
  float v = (G > 0.f) ? (1.f - score) : 0.f;
  #pragma unroll
  for (int d = 1; d < 64; d <<= 1) v += __shfl_xor(v, d, 64);
  __shared__ float sw[8];
  if ((k & 63) == 0) sw[k >> 6] = v;
  __syncthreads();
  if (k == 0) {
    float s = 0.f;
    #pragma unroll
    for (int i = 0; i < 8; ++i) s += sw[i];
    out[0] = s / (float)KDIM;
  }
}

extern "C" void kernel_launch(void* const* d_in, const int* in_sizes, int n_in,
                              void* d_out, int out_size, void* d_ws, size_t ws_size,
                              hipStream_t stream) {
  const float* X   = (const float*)d_in[0];   // [8,512,128,128] fp32
  const float* ANN = (const float*)d_in[1];   // [8,512,128,128] fp32 one-hot
  const float* E   = (const float*)d_in[2];   // [512,512] fp32

  char* base = (char*)d_ws;
  unsigned short* Eb = (unsigned short*)base;                 // 512 KiB
  float* gt_count    = (float*)(base + 524288);
  int*   pred_count  = (int*)  (base + 524288 + 2048);
  int*   inter       = (int*)  (base + 524288 + 4096);

  hipMemsetAsync(base + 524288, 0, 6144, stream);
  prep_emb_kernel<<<KDIM, 64, 0, stream>>>(E, Eb);
  gemm_fused<<<NPIX / 64, 256, 0, stream>>>(X, ANN, Eb, gt_count, pred_count, inter);
  final_kernel<<<1, 512, 0, stream>>>(pred_count, inter, gt_count, (float*)d_out);
}